// Round 13
// baseline (98.850 us; speedup 1.0000x reference)
//
#include <hip/hip_runtime.h>
#include <hip/hip_bf16.h>

#define IN_DIMX 135909
#define OUT_DIMX 670091
#define DDIM 128
#define BATCH 256
#define TFEAT 100
#define NBLK 512                      // k_lse grid: exactly 2 blocks/CU
#define NCHUNK ((OUT_DIMX + 63) / 64) // 10471 chunks of 64 classes
#define LOG2E 1.44269504088896f

typedef __bf16 bf16_t;
typedef __attribute__((ext_vector_type(4))) float f32x4;

// ---------------- K1: embedding bag sum -> L2 normalize -> +bias -> relu ----
// fp8 pack of q PRE-SCALED by log2e (k_lse consumes exp2-domain logits);
// qf stays exact f32 for the label-logit path.
__global__ void k_query(const int* __restrict__ x, const float* __restrict__ emb,
                        const float* __restrict__ bias, float* __restrict__ qf,
                        unsigned char* __restrict__ q8) {
    const int row = blockIdx.x;
    const int t = threadIdx.x; // 128 threads, one per dim
    __shared__ int sidx[TFEAT];
    __shared__ float qs[DDIM];
    if (t < TFEAT) sidx[t] = x[row * TFEAT + t];
    __syncthreads();
    float s = 0.f;
    #pragma unroll 10
    for (int i = 0; i < TFEAT; ++i) {
        s += emb[(size_t)sidx[i] * DDIM + t];
    }
    float sq = s * s;
    #pragma unroll
    for (int off = 1; off < 64; off <<= 1) sq += __shfl_xor(sq, off, 64);
    __shared__ float wred[2];
    if ((t & 63) == 0) wred[t >> 6] = sq;
    __syncthreads();
    const float tot = wred[0] + wred[1];
    float q = s / sqrtf(tot) + bias[t];
    q = fmaxf(q, 0.f);
    qf[row * DDIM + t] = q;
    qs[t] = q * LOG2E; // exp2-domain prescale for k_lse
    __syncthreads();
    if (t < 32) { // pack 4 dims/thread into fp8 e4m3
        int p = __builtin_amdgcn_cvt_pk_fp8_f32(qs[4 * t], qs[4 * t + 1], 0, false);
        p = __builtin_amdgcn_cvt_pk_fp8_f32(qs[4 * t + 2], qs[4 * t + 3], p, true);
        ((int*)q8)[row * 32 + t] = p;
    }
}

// ---------------- K2: MFMA logits + per-block partial sum-of-exp ------------
// R11 skeleton (proven 84.0us) with critical-path cuts:
//  - bias folded into MFMA C-init (acc starts at bo, per-lane class bias)
//  - exp2-domain (q,bo prescaled by log2e): consume = v_exp + v_add only
//  - reordered: MFMA(cur) -> convwrite_reload(cur^1) -> consume -> barrier.
//    Writes target the OPPOSITE buffer from reads, so the vmcnt wait is off
//    the critical path and prefetched loads fly ~1.5 chunk-periods.
// Buffer discipline: iter reads lds[cur], writes lds[cur^1]; the single raw
// barrier (lgkmcnt only, no vmcnt drain) separates all reads of cur from the
// next iteration's overwrite of cur.
__global__ __launch_bounds__(256, 2)
void k_lse(const float* __restrict__ W, const float* __restrict__ b_out,
           const unsigned char* __restrict__ q8, float* __restrict__ partials) {
    __shared__ unsigned char lds[2][64 * DDIM]; // 2 x 8 KB fp8
    const int tid = threadIdx.x;
    const int lane = tid & 63;
    const int w = tid >> 6;
    const int l15 = lane & 15;
    const int l4 = lane >> 4;

    // A fragments: this wave's 64 batch rows, fp8 (8 bytes = i64 per frag)
    long a[4][4];
    #pragma unroll
    for (int mt = 0; mt < 4; ++mt)
        #pragma unroll
        for (int ks = 0; ks < 4; ++ks)
            a[mt][ks] = *(const long*)(q8 + (w * 64 + mt * 16 + l15) * DDIM + ks * 32 + 8 * l4);

    float rs[4][4];
    #pragma unroll
    for (int mt = 0; mt < 4; ++mt)
        #pragma unroll
        for (int r = 0; r < 4; ++r) rs[mt][r] = 0.f;

    // staging geometry: thread covers f32 elems (row = j*8 + tid>>5,
    // cols [(tid&31)*4, +4)); global access per j = contiguous 1KB/wave.
    const int srow = tid >> 5;
    const int scol4 = (tid & 31);       // 4-byte fp8 group index 0..31
    const int c8 = scol4 >> 1;          // dest 8B granule within row
    const int half = (scol4 & 1) * 4;   // byte offset within granule

    f32x4 wr[8];
    float bo_c[4], bo_n[4];

    auto issue = [&](int ch, float (&bo)[4]) {
        const int cb = ch * 64;
        #pragma unroll
        for (int j = 0; j < 8; ++j) {
            int r = cb + j * 8 + srow;
            r = (r < OUT_DIMX) ? r : 0; // clamp: unconditional, in-bounds
            wr[j] = *(const f32x4*)(W + (size_t)r * DDIM + scol4 * 4);
        }
        #pragma unroll
        for (int nt = 0; nt < 4; ++nt) {
            int cc = cb + nt * 16 + l15;
            cc = (cc < OUT_DIMX) ? cc : 0;
            bo[nt] = b_out[cc] * LOG2E; // exp2-domain
        }
    };

    // pack wr -> fp8 into lds[buf]; per j immediately reload wr[j] (+bo_n)
    // for chunk nch. Loads ride across consume + barrier + next MFMA.
    auto convwrite_reload = [&](int buf, bool do_reload, int nch) {
        const int cb = nch * 64;
        #pragma unroll
        for (int j = 0; j < 8; ++j) {
            const int row = j * 8 + srow;
            const int sw = (c8 ^ (row & 7)) * 8 + half;
            int p = __builtin_amdgcn_cvt_pk_fp8_f32(wr[j][0], wr[j][1], 0, false);
            p = __builtin_amdgcn_cvt_pk_fp8_f32(wr[j][2], wr[j][3], p, true);
            *(int*)(&lds[buf][row * DDIM + sw]) = p;
            if (do_reload) {
                int r = cb + j * 8 + srow;
                r = (r < OUT_DIMX) ? r : 0;
                wr[j] = *(const f32x4*)(W + (size_t)r * DDIM + scol4 * 4);
            }
        }
        if (do_reload) {
            #pragma unroll
            for (int nt = 0; nt < 4; ++nt) {
                int cc = cb + nt * 16 + l15;
                cc = (cc < OUT_DIMX) ? cc : 0;
                bo_n[nt] = b_out[cc] * LOG2E;
            }
        }
    };

    // Prologue: chunk c0 staged to lds[0]; chunk c1 loads in flight.
    const int c0 = blockIdx.x;
    issue(c0, bo_c);
    convwrite_reload(0, false, 0);          // pack c0 (vmcnt waits c0 loads)
    {
        const int c1 = c0 + NBLK;
        issue(c1 < NCHUNK ? c1 : 0, bo_n);  // c1 loads fly across barrier
    }
    asm volatile("s_waitcnt lgkmcnt(0)" ::: "memory");
    __builtin_amdgcn_s_barrier();
    asm volatile("" ::: "memory");

    int cur = 0;
    for (int ch = c0; ch < NCHUNK; ch += NBLK) {
        // lds[cur] = ch; wr/bo_n = ch+1 (in flight); bo_c = bo(ch)
        f32x4 acc[4][4];
        #pragma unroll
        for (int mt = 0; mt < 4; ++mt)
            #pragma unroll
            for (int nt = 0; nt < 4; ++nt)
                acc[mt][nt] = (f32x4){bo_c[nt], bo_c[nt], bo_c[nt], bo_c[nt]};

        #pragma unroll
        for (int ks = 0; ks < 4; ++ks) {
            #pragma unroll
            for (int nt = 0; nt < 4; ++nt) {
                const int row = nt * 16 + l15;
                const int g = (ks * 4 + l4) ^ (row & 7);
                const long b = *(const long*)(&lds[cur][row * DDIM + g * 8]);
                #pragma unroll
                for (int mt = 0; mt < 4; ++mt)
                    acc[mt][nt] = __builtin_amdgcn_mfma_f32_16x16x32_fp8_fp8(
                        a[mt][ks], b, acc[mt][nt], 0, 0, 0);
            }
        }

        // stage ch+1 into the OTHER buffer (reads of cur unaffected);
        // reload ch+2 into wr; advance bias pipeline.
        const bool has_next = (ch + NBLK < NCHUNK);
        if (has_next) {
            #pragma unroll
            for (int nt = 0; nt < 4; ++nt) bo_c[nt] = bo_n[nt];
            const int c2 = ch + 2 * NBLK;
            convwrite_reload(cur ^ 1, c2 < NCHUNK, c2 < NCHUNK ? c2 : 0);
        }

        // consume: rs += exp2(acc)  (bias already in acc; exp2-domain)
        const int cbase = ch * 64;
        if (cbase + 64 <= OUT_DIMX) { // full chunk: no masking
            #pragma unroll
            for (int nt = 0; nt < 4; ++nt)
                #pragma unroll
                for (int mt = 0; mt < 4; ++mt)
                    #pragma unroll
                    for (int r = 0; r < 4; ++r)
                        rs[mt][r] += __builtin_amdgcn_exp2f(acc[mt][nt][r]);
        } else { // single partial tail chunk
            #pragma unroll
            for (int nt = 0; nt < 4; ++nt) {
                const bool valid = (cbase + nt * 16 + l15 < OUT_DIMX);
                #pragma unroll
                for (int mt = 0; mt < 4; ++mt)
                    #pragma unroll
                    for (int r = 0; r < 4; ++r)
                        rs[mt][r] += valid ? __builtin_amdgcn_exp2f(acc[mt][nt][r]) : 0.f;
            }
        }

        // publish lds[cur^1] (ds_writes) and protect cur for overwrite next iter
        asm volatile("s_waitcnt lgkmcnt(0)" ::: "memory");
        __builtin_amdgcn_s_barrier();
        asm volatile("" ::: "memory");
        cur ^= 1;
    }

    // reduce across the 16 lanes sharing each batch row; transposed layout
    // partials[row * NBLK + blk] so k_rowlse reads coalesced.
    #pragma unroll
    for (int mt = 0; mt < 4; ++mt)
        #pragma unroll
        for (int r = 0; r < 4; ++r) {
            float v = rs[mt][r];
            v += __shfl_xor(v, 1, 64);
            v += __shfl_xor(v, 2, 64);
            v += __shfl_xor(v, 4, 64);
            v += __shfl_xor(v, 8, 64);
            if (l15 == 0) {
                const int rowb = w * 64 + mt * 16 + l4 * 4 + r;
                partials[(size_t)rowb * NBLK + blockIdx.x] = v;
            }
        }
}

// ---------------- K3: per-row logsumexp + label logit -> per-row loss -------
// partials hold sums of 2^(l*log2e) = e^l, so LSE_natural = logf(s). (R12's
// bug was an extra *ln2 here.)
__global__ void k_rowlse(const float* __restrict__ partials,
                         const int* __restrict__ y,
                         const float* __restrict__ qf,
                         const float* __restrict__ W,
                         const float* __restrict__ b_out,
                         float* __restrict__ rowloss) {
    const int i = blockIdx.x;     // batch row
    const int lane = threadIdx.x; // 64
    float s = 0.f;
    #pragma unroll
    for (int k = 0; k < NBLK / 64; ++k)
        s += partials[(size_t)i * NBLK + k * 64 + lane];
    // label logit: dot(q_i, W[y_i]) fused here (exact f32)
    const int yi = y[i];
    const float* wrow = W + (size_t)yi * DDIM;
    const float* qrow = qf + i * DDIM;
    float d = qrow[lane] * wrow[lane] + qrow[lane + 64] * wrow[lane + 64];
    #pragma unroll
    for (int off = 1; off < 64; off <<= 1) {
        s += __shfl_xor(s, off, 64);
        d += __shfl_xor(d, off, 64);
    }
    if (lane == 0) rowloss[i] = logf(s) - (d + b_out[yi]);
}

// ---------------- K4: mean over batch -> scalar loss ------------------------
__global__ void k_final(const float* __restrict__ rowloss, float* __restrict__ out) {
    const int i = threadIdx.x; // 256
    float t = rowloss[i];
    #pragma unroll
    for (int off = 1; off < 64; off <<= 1) t += __shfl_xor(t, off, 64);
    __shared__ float wred[4];
    if ((threadIdx.x & 63) == 0) wred[threadIdx.x >> 6] = t;
    __syncthreads();
    if (threadIdx.x == 0)
        out[0] = (wred[0] + wred[1] + wred[2] + wred[3]) * (1.0f / (float)BATCH);
}

extern "C" void kernel_launch(void* const* d_in, const int* in_sizes, int n_in,
                              void* d_out, int out_size, void* d_ws, size_t ws_size,
                              hipStream_t stream) {
    const int*   x     = (const int*)d_in[0];
    const int*   y     = (const int*)d_in[1];
    // d_in[2] = freeze, d_in[3] = slide (unused: exact/full softmax path)
    const float* emb   = (const float*)d_in[4];
    const float* bias  = (const float*)d_in[5];
    const float* W     = (const float*)d_in[6];
    const float* b_out = (const float*)d_in[7];
    float* out = (float*)d_out;

    char* ws = (char*)d_ws;
    unsigned char* q8 = (unsigned char*)(ws);   // 256*128 = 32 KB fp8 (q*log2e)
    float*  qf       = (float*)(ws + 65536);    // 256*128*4 = 128 KB (exact)
    float*  rowloss  = (float*)(ws + 197632);   // 1 KB
    float*  partials = (float*)(ws + 262144);   // 256*NBLK*4 = 512 KB

    k_query<<<BATCH, DDIM, 0, stream>>>(x, emb, bias, qf, q8);
    k_lse<<<NBLK, 256, 0, stream>>>(W, b_out, q8, partials);
    k_rowlse<<<BATCH, 64, 0, stream>>>(partials, y, qf, W, b_out, rowloss);
    k_final<<<1, 256, 0, stream>>>(rowloss, out);
}

// Round 14
// 82.215 us; speedup vs baseline: 1.2023x; 1.2023x over previous
//
#include <hip/hip_runtime.h>
#include <hip/hip_bf16.h>

#define IN_DIMX 135909
#define OUT_DIMX 670091
#define DDIM 128
#define BATCH 256
#define TFEAT 100
#define NBLK 512                      // k_lse grid: exactly 2 blocks/CU
#define NCHUNK ((OUT_DIMX + 63) / 64) // 10471 chunks of 64 classes
#define LOG2E 1.44269504088896f

typedef __bf16 bf16_t;
typedef __attribute__((ext_vector_type(4))) float f32x4;

// ---------------- K1: embedding bag sum -> L2 normalize -> +bias -> relu ----
// fp8 pack of q PRE-SCALED by log2e (k_lse consumes exp2-domain logits);
// qf stays exact f32 for the label-logit path.
__global__ void k_query(const int* __restrict__ x, const float* __restrict__ emb,
                        const float* __restrict__ bias, float* __restrict__ qf,
                        unsigned char* __restrict__ q8) {
    const int row = blockIdx.x;
    const int t = threadIdx.x; // 128 threads, one per dim
    __shared__ int sidx[TFEAT];
    __shared__ float qs[DDIM];
    if (t < TFEAT) sidx[t] = x[row * TFEAT + t];
    __syncthreads();
    float s = 0.f;
    #pragma unroll 10
    for (int i = 0; i < TFEAT; ++i) {
        s += emb[(size_t)sidx[i] * DDIM + t];
    }
    float sq = s * s;
    #pragma unroll
    for (int off = 1; off < 64; off <<= 1) sq += __shfl_xor(sq, off, 64);
    __shared__ float wred[2];
    if ((t & 63) == 0) wred[t >> 6] = sq;
    __syncthreads();
    const float tot = wred[0] + wred[1];
    float q = s / sqrtf(tot) + bias[t];
    q = fmaxf(q, 0.f);
    qf[row * DDIM + t] = q;
    qs[t] = q * LOG2E; // exp2-domain prescale for k_lse
    __syncthreads();
    if (t < 32) { // pack 4 dims/thread into fp8 e4m3
        int p = __builtin_amdgcn_cvt_pk_fp8_f32(qs[4 * t], qs[4 * t + 1], 0, false);
        p = __builtin_amdgcn_cvt_pk_fp8_f32(qs[4 * t + 2], qs[4 * t + 3], p, true);
        ((int*)q8)[row * 32 + t] = p;
    }
}

// ---------------- K2: MFMA logits + per-block partial sum-of-exp ------------
// R11 skeleton with R11's EXACT ordering (proven 84.0us): per chunk,
// convwrite_reload (pack wr -> fp8 -> lds[cur], reload wr in place with next
// chunk; loads ride across the raw barrier) -> lgkmcnt(0)+s_barrier (no vmcnt
// drain) -> MFMA from lds[cur] -> consume. ONLY two pure-deletion changes vs
// R11 (disentangled from R13's losing reorder):
//  - bias folded into MFMA C-init: acc starts at bo (deletes 64 v_add/chunk)
//  - exp2 domain (q8, bo prescaled by log2e): consume = exp2 only (deletes
//    64 v_mul/chunk); k_rowlse uses logf(s) directly (R13-verified).
__global__ __launch_bounds__(256, 2)
void k_lse(const float* __restrict__ W, const float* __restrict__ b_out,
           const unsigned char* __restrict__ q8, float* __restrict__ partials) {
    __shared__ unsigned char lds[2][64 * DDIM]; // 2 x 8 KB fp8
    const int tid = threadIdx.x;
    const int lane = tid & 63;
    const int w = tid >> 6;
    const int l15 = lane & 15;
    const int l4 = lane >> 4;

    // A fragments: this wave's 64 batch rows, fp8 (8 bytes = i64 per frag)
    long a[4][4];
    #pragma unroll
    for (int mt = 0; mt < 4; ++mt)
        #pragma unroll
        for (int ks = 0; ks < 4; ++ks)
            a[mt][ks] = *(const long*)(q8 + (w * 64 + mt * 16 + l15) * DDIM + ks * 32 + 8 * l4);

    float rs[4][4];
    #pragma unroll
    for (int mt = 0; mt < 4; ++mt)
        #pragma unroll
        for (int r = 0; r < 4; ++r) rs[mt][r] = 0.f;

    // staging geometry: thread covers f32 elems (row = j*8 + tid>>5,
    // cols [(tid&31)*4, +4)); global access per j = contiguous 1KB/wave.
    const int srow = tid >> 5;
    const int scol4 = (tid & 31);       // 4-byte fp8 group index 0..31
    const int c8 = scol4 >> 1;          // dest 8B granule within row
    const int half = (scol4 & 1) * 4;   // byte offset within granule

    f32x4 wr[8];
    float bo_n[4];

    auto issue = [&](int ch) {
        const int cb = ch * 64;
        #pragma unroll
        for (int j = 0; j < 8; ++j) {
            int r = cb + j * 8 + srow;
            r = (r < OUT_DIMX) ? r : 0; // clamp: unconditional, in-bounds
            wr[j] = *(const f32x4*)(W + (size_t)r * DDIM + scol4 * 4);
        }
        #pragma unroll
        for (int nt = 0; nt < 4; ++nt) {
            int cc = cb + nt * 16 + l15;
            cc = (cc < OUT_DIMX) ? cc : 0;
            bo_n[nt] = b_out[cc] * LOG2E; // exp2-domain
        }
    };

    // Fused: per j, pack wr[j] -> 4 fp8 bytes, ds_write_b32, then immediately
    // reload wr[j] with the next chunk's row j (loads ride across the barrier).
    auto convwrite_reload = [&](int cur, bool has_next, int nch) {
        const int cb = nch * 64;
        #pragma unroll
        for (int j = 0; j < 8; ++j) {
            const int row = j * 8 + srow;
            const int sw = (c8 ^ (row & 7)) * 8 + half;
            int p = __builtin_amdgcn_cvt_pk_fp8_f32(wr[j][0], wr[j][1], 0, false);
            p = __builtin_amdgcn_cvt_pk_fp8_f32(wr[j][2], wr[j][3], p, true);
            *(int*)(&lds[cur][row * DDIM + sw]) = p;
            if (has_next) {
                int r = cb + j * 8 + srow;
                r = (r < OUT_DIMX) ? r : 0;
                wr[j] = *(const f32x4*)(W + (size_t)r * DDIM + scol4 * 4);
            }
        }
    };

    int cur = 0;
    issue(blockIdx.x);
    for (int ch = blockIdx.x; ch < NCHUNK; ch += NBLK) {
        float bo_c[4];
        #pragma unroll
        for (int nt = 0; nt < 4; ++nt) bo_c[nt] = bo_n[nt];

        const bool has_next = (ch + NBLK < NCHUNK);
        convwrite_reload(cur, has_next, has_next ? ch + NBLK : 0);
        if (has_next) { // next chunk's b_out rides with the W loads
            const int cb = (ch + NBLK) * 64;
            #pragma unroll
            for (int nt = 0; nt < 4; ++nt) {
                int cc = cb + nt * 16 + l15;
                cc = (cc < OUT_DIMX) ? cc : 0;
                bo_n[nt] = b_out[cc] * LOG2E;
            }
        }
        // RAW barrier: wait only LDS writes; W loads stay in flight across it.
        asm volatile("s_waitcnt lgkmcnt(0)" ::: "memory");
        __builtin_amdgcn_s_barrier();
        asm volatile("" ::: "memory"); // no ds_read hoist above barrier

        f32x4 acc[4][4]; // C-init = per-class bias (exp2-domain)
        #pragma unroll
        for (int mt = 0; mt < 4; ++mt)
            #pragma unroll
            for (int nt = 0; nt < 4; ++nt)
                acc[mt][nt] = (f32x4){bo_c[nt], bo_c[nt], bo_c[nt], bo_c[nt]};

        #pragma unroll
        for (int ks = 0; ks < 4; ++ks) {
            #pragma unroll
            for (int nt = 0; nt < 4; ++nt) {
                const int row = nt * 16 + l15;
                const int g = (ks * 4 + l4) ^ (row & 7);
                const long b = *(const long*)(&lds[cur][row * DDIM + g * 8]);
                #pragma unroll
                for (int mt = 0; mt < 4; ++mt)
                    acc[mt][nt] = __builtin_amdgcn_mfma_f32_16x16x32_fp8_fp8(
                        a[mt][ks], b, acc[mt][nt], 0, 0, 0);
            }
        }

        // consume: rs += exp2(acc)  (bias already in acc; exp2-domain)
        const int cbase = ch * 64;
        if (cbase + 64 <= OUT_DIMX) { // full chunk: no masking
            #pragma unroll
            for (int nt = 0; nt < 4; ++nt)
                #pragma unroll
                for (int mt = 0; mt < 4; ++mt)
                    #pragma unroll
                    for (int r = 0; r < 4; ++r)
                        rs[mt][r] += __builtin_amdgcn_exp2f(acc[mt][nt][r]);
        } else { // single partial tail chunk
            #pragma unroll
            for (int nt = 0; nt < 4; ++nt) {
                const bool valid = (cbase + nt * 16 + l15 < OUT_DIMX);
                #pragma unroll
                for (int mt = 0; mt < 4; ++mt)
                    #pragma unroll
                    for (int r = 0; r < 4; ++r)
                        rs[mt][r] += valid ? __builtin_amdgcn_exp2f(acc[mt][nt][r]) : 0.f;
            }
        }
        cur ^= 1;
    }

    // reduce across the 16 lanes sharing each batch row; transposed layout
    // partials[row * NBLK + blk] so k_rowlse reads coalesced.
    #pragma unroll
    for (int mt = 0; mt < 4; ++mt)
        #pragma unroll
        for (int r = 0; r < 4; ++r) {
            float v = rs[mt][r];
            v += __shfl_xor(v, 1, 64);
            v += __shfl_xor(v, 2, 64);
            v += __shfl_xor(v, 4, 64);
            v += __shfl_xor(v, 8, 64);
            if (l15 == 0) {
                const int rowb = w * 64 + mt * 16 + l4 * 4 + r;
                partials[(size_t)rowb * NBLK + blockIdx.x] = v;
            }
        }
}

// ---------------- K3: per-row logsumexp + label logit -> per-row loss -------
// partials hold sums of 2^(l*log2e) = e^l, so LSE_natural = logf(s).
__global__ void k_rowlse(const float* __restrict__ partials,
                         const int* __restrict__ y,
                         const float* __restrict__ qf,
                         const float* __restrict__ W,
                         const float* __restrict__ b_out,
                         float* __restrict__ rowloss) {
    const int i = blockIdx.x;     // batch row
    const int lane = threadIdx.x; // 64
    float s = 0.f;
    #pragma unroll
    for (int k = 0; k < NBLK / 64; ++k)
        s += partials[(size_t)i * NBLK + k * 64 + lane];
    // label logit: dot(q_i, W[y_i]) fused here (exact f32)
    const int yi = y[i];
    const float* wrow = W + (size_t)yi * DDIM;
    const float* qrow = qf + i * DDIM;
    float d = qrow[lane] * wrow[lane] + qrow[lane + 64] * wrow[lane + 64];
    #pragma unroll
    for (int off = 1; off < 64; off <<= 1) {
        s += __shfl_xor(s, off, 64);
        d += __shfl_xor(d, off, 64);
    }
    if (lane == 0) rowloss[i] = logf(s) - (d + b_out[yi]);
}

// ---------------- K4: mean over batch -> scalar loss ------------------------
__global__ void k_final(const float* __restrict__ rowloss, float* __restrict__ out) {
    const int i = threadIdx.x; // 256
    float t = rowloss[i];
    #pragma unroll
    for (int off = 1; off < 64; off <<= 1) t += __shfl_xor(t, off, 64);
    __shared__ float wred[4];
    if ((threadIdx.x & 63) == 0) wred[threadIdx.x >> 6] = t;
    __syncthreads();
    if (threadIdx.x == 0)
        out[0] = (wred[0] + wred[1] + wred[2] + wred[3]) * (1.0f / (float)BATCH);
}

extern "C" void kernel_launch(void* const* d_in, const int* in_sizes, int n_in,
                              void* d_out, int out_size, void* d_ws, size_t ws_size,
                              hipStream_t stream) {
    const int*   x     = (const int*)d_in[0];
    const int*   y     = (const int*)d_in[1];
    // d_in[2] = freeze, d_in[3] = slide (unused: exact/full softmax path)
    const float* emb   = (const float*)d_in[4];
    const float* bias  = (const float*)d_in[5];
    const float* W     = (const float*)d_in[6];
    const float* b_out = (const float*)d_in[7];
    float* out = (float*)d_out;

    char* ws = (char*)d_ws;
    unsigned char* q8 = (unsigned char*)(ws);   // 256*128 = 32 KB fp8 (q*log2e)
    float*  qf       = (float*)(ws + 65536);    // 256*128*4 = 128 KB (exact)
    float*  rowloss  = (float*)(ws + 197632);   // 1 KB
    float*  partials = (float*)(ws + 262144);   // 256*NBLK*4 = 512 KB

    k_query<<<BATCH, DDIM, 0, stream>>>(x, emb, bias, qf, q8);
    k_lse<<<NBLK, 256, 0, stream>>>(W, b_out, q8, partials);
    k_rowlse<<<BATCH, 64, 0, stream>>>(partials, y, qf, W, b_out, rowloss);
    k_final<<<1, 256, 0, stream>>>(rowloss, out);
}